// Round 5
// baseline (133.588 us; speedup 1.0000x reference)
//
#include <hip/hip_runtime.h>

// Problem constants: B=16, NEG=128, S=128, D=512, N_PRED=12
#define DIM 512
#define M_ROWS 2048      // B*S

typedef __attribute__((ext_vector_type(8))) short short8;   // 8 bf16 (4 VGPRs)
typedef __attribute__((ext_vector_type(4))) float f32x4;

// f32 -> bf16 round-to-nearest-even (inputs are well-scaled, no NaN expected)
static __device__ __forceinline__ short f2bf(float x) {
    unsigned int u = __builtin_bit_cast(unsigned int, x);
    u += 0x7fffu + ((u >> 16) & 1u);
    return (short)(u >> 16);
}

// ---------------- Kernel 1: c_proj = c @ W[k]^T + b[k], bf16 MFMA ----------------
// (unchanged from R3 — ~3-5 us, verified absmax 9.8e-4)
#define K1_PAD 40
__global__ __launch_bounds__(256) void cproj_mfma(
    const float* __restrict__ c, const float* __restrict__ W,
    const float* __restrict__ bias, const int* __restrict__ kptr,
    float* __restrict__ cp) {
    const int ksel = kptr[0];
    const float* __restrict__ Wk = W + (size_t)ksel * DIM * DIM;
    const float* __restrict__ bk = bias + (size_t)ksel * DIM;

    __shared__ short Alds[64][K1_PAD];
    __shared__ short Blds[64][K1_PAD];

    const int bm = blockIdx.x & 31;     // m-tile (64 rows)
    const int bn = blockIdx.x >> 5;     // n-tile (64 cols)
    const int t  = threadIdx.x;
    const int lane = t & 63;
    const int wv   = t >> 6;            // wave 0..3

    const int srow = t >> 2;            // 0..63
    const int sk   = (t & 3) * 8;       // 0,8,16,24

    const float* Ap = c  + (size_t)(bm * 64 + srow) * DIM + sk;
    const float* Bp = Wk + (size_t)(bn * 64 + srow) * DIM + sk;

    float4 a0 = *(const float4*)Ap,       a1 = *(const float4*)(Ap + 4);
    float4 b0 = *(const float4*)Bp,       b1 = *(const float4*)(Bp + 4);

    f32x4 acc[4] = {};                  // 4 m-subtiles of 16x16

    const int frow = lane & 15;
    const int fk   = (lane >> 4) * 8;

    for (int step = 0; step < 16; ++step) {
        __syncthreads();                // previous step's frag reads complete
        short8 av, bv;
        av[0] = f2bf(a0.x); av[1] = f2bf(a0.y); av[2] = f2bf(a0.z); av[3] = f2bf(a0.w);
        av[4] = f2bf(a1.x); av[5] = f2bf(a1.y); av[6] = f2bf(a1.z); av[7] = f2bf(a1.w);
        bv[0] = f2bf(b0.x); bv[1] = f2bf(b0.y); bv[2] = f2bf(b0.z); bv[3] = f2bf(b0.w);
        bv[4] = f2bf(b1.x); bv[5] = f2bf(b1.y); bv[6] = f2bf(b1.z); bv[7] = f2bf(b1.w);
        *(short8*)&Alds[srow][sk] = av;
        *(short8*)&Blds[srow][sk] = bv;
        __syncthreads();
        if (step < 15) {
            const int off = (step + 1) * 32;
            a0 = *(const float4*)(Ap + off); a1 = *(const float4*)(Ap + off + 4);
            b0 = *(const float4*)(Bp + off); b1 = *(const float4*)(Bp + off + 4);
        }
        const short8 bfrag = *(const short8*)&Blds[wv * 16 + frow][fk];
#pragma unroll
        for (int f = 0; f < 4; ++f) {
            const short8 afrag = *(const short8*)&Alds[f * 16 + frow][fk];
            acc[f] = __builtin_amdgcn_mfma_f32_16x16x32_bf16(afrag, bfrag, acc[f], 0, 0, 0);
        }
    }

    const int col = bn * 64 + wv * 16 + frow;
    const float bias_v = bk[col];
    const int r0 = (lane >> 4) * 4;
#pragma unroll
    for (int f = 0; f < 4; ++f)
#pragma unroll
        for (int r = 0; r < 4; ++r)
            cp[(size_t)(bm * 64 + f * 16 + r0 + r) * DIM + col] = acc[f][r] + bias_v;
}

// ---------------- Kernel 2: out[b,n,s] = (1/512) * dot(cp[b,s,:], z[b,n,s,:]) ----
// Block = (b,n): each block streams ONE CONTIGUOUS 256 KB region z[b,n,:,:]
// (sequential DRAM pages), reading cp[b,s,:] from L2 per iteration.
// XCD remap: XCD x gets b in {2x, 2x+1} -> 512 KB of cp resident per XCD L2.
// Each wave: 2 adjacent s-rows per iter (two independent reduce chains for
// shuffle ILP, 4 KB z in flight), 1-deep prefetch on z and cp.
#define LD4(p) (*(const float4*)(p))
__global__ __launch_bounds__(256) void dot_kernel2(
    const float* __restrict__ z, const float* __restrict__ cp,
    float* __restrict__ out) {
    const int j = blockIdx.x;
    const int r = j >> 3;                        // rank within XCD (0..255)
    const int b = ((j & 7) << 1) | (r >> 7);     // 2*xcd + hi-bit
    const int n = r & 127;
    const int wave = threadIdx.x >> 6;
    const int lane = threadIdx.x & 63;

    // wave handles s = i*8 + wave*2 + {0,1}, i = 0..15
    const float* zp  = z  + (((size_t)(b * 128 + n) * 128 + wave * 2) * DIM) + lane * 8;
    const float* cpp = cp + (((size_t)b * 128 + wave * 2) * DIM) + lane * 8;
    float* outp = out + ((size_t)(b * 128 + n)) * 128 + wave * 2;

    float4 za0 = LD4(zp),         za1 = LD4(zp + 4);
    float4 zb0 = LD4(zp + DIM),   zb1 = LD4(zp + DIM + 4);
    float4 ca0 = LD4(cpp),        ca1 = LD4(cpp + 4);
    float4 cb0 = LD4(cpp + DIM),  cb1 = LD4(cpp + DIM + 4);

#pragma unroll 4
    for (int i = 0; i < 16; ++i) {
        const float4 ya0 = za0, ya1 = za1, yb0 = zb0, yb1 = zb1;
        const float4 da0 = ca0, da1 = ca1, db0 = cb0, db1 = cb1;
        if (i < 15) {   // prefetch next 2 s-rows (z: +4 KB sequential)
            zp  += 8 * DIM;
            cpp += 8 * DIM;
            za0 = LD4(zp);        za1 = LD4(zp + 4);
            zb0 = LD4(zp + DIM);  zb1 = LD4(zp + DIM + 4);
            ca0 = LD4(cpp);       ca1 = LD4(cpp + 4);
            cb0 = LD4(cpp + DIM); cb1 = LD4(cpp + DIM + 4);
        }
        float acc0 = ya0.x * da0.x;
        acc0 = fmaf(ya0.y, da0.y, acc0);
        acc0 = fmaf(ya0.z, da0.z, acc0);
        acc0 = fmaf(ya0.w, da0.w, acc0);
        acc0 = fmaf(ya1.x, da1.x, acc0);
        acc0 = fmaf(ya1.y, da1.y, acc0);
        acc0 = fmaf(ya1.z, da1.z, acc0);
        acc0 = fmaf(ya1.w, da1.w, acc0);
        float acc1 = yb0.x * db0.x;
        acc1 = fmaf(yb0.y, db0.y, acc1);
        acc1 = fmaf(yb0.z, db0.z, acc1);
        acc1 = fmaf(yb0.w, db0.w, acc1);
        acc1 = fmaf(yb1.x, db1.x, acc1);
        acc1 = fmaf(yb1.y, db1.y, acc1);
        acc1 = fmaf(yb1.z, db1.z, acc1);
        acc1 = fmaf(yb1.w, db1.w, acc1);
#pragma unroll
        for (int off = 32; off; off >>= 1) {
            acc0 += __shfl_xor(acc0, off);
            acc1 += __shfl_xor(acc1, off);
        }
        if (lane == 0) {
            float2 o2;
            o2.x = acc0 * (1.0f / 512.0f);
            o2.y = acc1 * (1.0f / 512.0f);
            *(float2*)outp = o2;
        }
        outp += 8;
    }
}

extern "C" void kernel_launch(void* const* d_in, const int* in_sizes, int n_in,
                              void* d_out, int out_size, void* d_ws, size_t ws_size,
                              hipStream_t stream) {
    const float* c    = (const float*)d_in[0];
    const float* z    = (const float*)d_in[1];
    const float* W    = (const float*)d_in[2];
    const float* bias = (const float*)d_in[3];
    const int*   kptr = (const int*)d_in[4];
    float* out = (float*)d_out;
    float* cp  = (float*)d_ws;   // 2048*512*4 = 4 MB scratch for c_proj

    // Kernel 1: 32 M-tiles x 8 N-tiles = 256 blocks, bf16 MFMA
    cproj_mfma<<<dim3(256), dim3(256), 0, stream>>>(c, W, bias, kptr, cp);
    // Kernel 2: one block per (b,n) = 2048 blocks, 4 waves, contiguous z stream
    dot_kernel2<<<dim3(2048), dim3(256), 0, stream>>>(z, cp, out);
}

// Round 6
// 119.855 us; speedup vs baseline: 1.1146x; 1.1146x over previous
//
#include <hip/hip_runtime.h>

// Problem constants: B=16, NEG=128, S=128, D=512, N_PRED=12
#define DIM 512
#define M_ROWS 2048      // B*S

typedef __attribute__((ext_vector_type(8))) short short8;   // 8 bf16 (4 VGPRs)
typedef __attribute__((ext_vector_type(4))) float f32x4;

// f32 -> bf16 round-to-nearest-even (inputs are well-scaled, no NaN expected)
static __device__ __forceinline__ short f2bf(float x) {
    unsigned int u = __builtin_bit_cast(unsigned int, x);
    u += 0x7fffu + ((u >> 16) & 1u);
    return (short)(u >> 16);
}

// ---------------- Kernel 1: c_proj = c @ W[k]^T + b[k], bf16 MFMA ----------------
// (unchanged from R3 — ~4 us, verified)
#define K1_PAD 40
__global__ __launch_bounds__(256) void cproj_mfma(
    const float* __restrict__ c, const float* __restrict__ W,
    const float* __restrict__ bias, const int* __restrict__ kptr,
    float* __restrict__ cp) {
    const int ksel = kptr[0];
    const float* __restrict__ Wk = W + (size_t)ksel * DIM * DIM;
    const float* __restrict__ bk = bias + (size_t)ksel * DIM;

    __shared__ short Alds[64][K1_PAD];
    __shared__ short Blds[64][K1_PAD];

    const int bm = blockIdx.x & 31;
    const int bn = blockIdx.x >> 5;
    const int t  = threadIdx.x;
    const int lane = t & 63;
    const int wv   = t >> 6;

    const int srow = t >> 2;
    const int sk   = (t & 3) * 8;

    const float* Ap = c  + (size_t)(bm * 64 + srow) * DIM + sk;
    const float* Bp = Wk + (size_t)(bn * 64 + srow) * DIM + sk;

    float4 a0 = *(const float4*)Ap,       a1 = *(const float4*)(Ap + 4);
    float4 b0 = *(const float4*)Bp,       b1 = *(const float4*)(Bp + 4);

    f32x4 acc[4] = {};

    const int frow = lane & 15;
    const int fk   = (lane >> 4) * 8;

    for (int step = 0; step < 16; ++step) {
        __syncthreads();
        short8 av, bv;
        av[0] = f2bf(a0.x); av[1] = f2bf(a0.y); av[2] = f2bf(a0.z); av[3] = f2bf(a0.w);
        av[4] = f2bf(a1.x); av[5] = f2bf(a1.y); av[6] = f2bf(a1.z); av[7] = f2bf(a1.w);
        bv[0] = f2bf(b0.x); bv[1] = f2bf(b0.y); bv[2] = f2bf(b0.z); bv[3] = f2bf(b0.w);
        bv[4] = f2bf(b1.x); bv[5] = f2bf(b1.y); bv[6] = f2bf(b1.z); bv[7] = f2bf(b1.w);
        *(short8*)&Alds[srow][sk] = av;
        *(short8*)&Blds[srow][sk] = bv;
        __syncthreads();
        if (step < 15) {
            const int off = (step + 1) * 32;
            a0 = *(const float4*)(Ap + off); a1 = *(const float4*)(Ap + off + 4);
            b0 = *(const float4*)(Bp + off); b1 = *(const float4*)(Bp + off + 4);
        }
        const short8 bfrag = *(const short8*)&Blds[wv * 16 + frow][fk];
#pragma unroll
        for (int f = 0; f < 4; ++f) {
            const short8 afrag = *(const short8*)&Alds[f * 16 + frow][fk];
            acc[f] = __builtin_amdgcn_mfma_f32_16x16x32_bf16(afrag, bfrag, acc[f], 0, 0, 0);
        }
    }

    const int col = bn * 64 + wv * 16 + frow;
    const float bias_v = bk[col];
    const int r0 = (lane >> 4) * 4;
#pragma unroll
    for (int f = 0; f < 4; ++f)
#pragma unroll
        for (int r = 0; r < 4; ++r)
            cp[(size_t)(bm * 64 + f * 16 + r0 + r) * DIM + col] = acc[f][r] + bias_v;
}

// ---------------- Kernel 2: out[b,n,s] = (1/512) * dot(cp[b,s,:], z[b,n,s,:]) ----
// Block per (b,s) row; cp row held in registers (loaded once).
// 4-deep software pipeline over the n-stream: each wave keeps 4 n-slots of z
// in NAMED registers (static indexing), reloading each slot right after its
// FMA-consume and BEFORE the shuffle-reduce -> ~6-8 float4 loads (6-8 KB)
// outstanding per wave at all times. 6 waves/SIMD floor via launch_bounds.
#define NSTR ((size_t)4 * 128 * 512)   // 4 negatives ahead in z (floats)
#define LD4(p) (*(const float4*)(p))

__global__ __launch_bounds__(256, 6) void dot_kernel(
    const float* __restrict__ z, const float* __restrict__ cp,
    float* __restrict__ out) {
    const int bs   = blockIdx.x;             // b*128 + s (0..2047)
    const int wave = threadIdx.x >> 6;       // 0..3
    const int lane = threadIdx.x & 63;
    const int b = bs >> 7;
    const int s = bs & 127;

    // cp row -> registers (all 4 waves broadcast-read the same 2 KB via L1)
    const float* cpr = cp + (size_t)bs * DIM + lane * 8;
    const float4 c0 = LD4(cpr);
    const float4 c1 = LD4(cpr + 4);

    // wave handles n = wave + 4*i, i = 0..31
    const float* zp = z + (((size_t)(b * 128 + wave)) * 128 + s) * DIM + lane * 8;
    float* outp = out + ((size_t)b * 128 + wave) * 128 + s;

    // prologue: fill 4 pipeline slots (8 loads in flight)
    float4 zA0 = LD4(zp + 0 * NSTR), zA1 = LD4(zp + 0 * NSTR + 4);
    float4 zB0 = LD4(zp + 1 * NSTR), zB1 = LD4(zp + 1 * NSTR + 4);
    float4 zC0 = LD4(zp + 2 * NSTR), zC1 = LD4(zp + 2 * NSTR + 4);
    float4 zD0 = LD4(zp + 3 * NSTR), zD1 = LD4(zp + 3 * NSTR + 4);

#define SLOT(Z0, Z1, II)                                                      \
    {                                                                          \
        float acc = Z0.x * c0.x;                                               \
        acc = fmaf(Z0.y, c0.y, acc);                                           \
        acc = fmaf(Z0.z, c0.z, acc);                                           \
        acc = fmaf(Z0.w, c0.w, acc);                                           \
        acc = fmaf(Z1.x, c1.x, acc);                                           \
        acc = fmaf(Z1.y, c1.y, acc);                                           \
        acc = fmaf(Z1.z, c1.z, acc);                                           \
        acc = fmaf(Z1.w, c1.w, acc);                                           \
        if ((II) + 4 < 32) {  /* reload this slot 4 n-steps ahead */           \
            Z0 = LD4(zp + (size_t)((II) + 4) * NSTR);                          \
            Z1 = LD4(zp + (size_t)((II) + 4) * NSTR + 4);                      \
        }                                                                      \
        _Pragma("unroll")                                                      \
        for (int off = 32; off; off >>= 1) acc += __shfl_xor(acc, off);        \
        if (lane == 0) outp[(size_t)(II) * 4 * 128] = acc * (1.0f / 512.0f);   \
    }

#pragma unroll
    for (int g = 0; g < 8; ++g) {
        SLOT(zA0, zA1, g * 4 + 0)
        SLOT(zB0, zB1, g * 4 + 1)
        SLOT(zC0, zC1, g * 4 + 2)
        SLOT(zD0, zD1, g * 4 + 3)
    }
#undef SLOT
}

extern "C" void kernel_launch(void* const* d_in, const int* in_sizes, int n_in,
                              void* d_out, int out_size, void* d_ws, size_t ws_size,
                              hipStream_t stream) {
    const float* c    = (const float*)d_in[0];
    const float* z    = (const float*)d_in[1];
    const float* W    = (const float*)d_in[2];
    const float* bias = (const float*)d_in[3];
    const int*   kptr = (const int*)d_in[4];
    float* out = (float*)d_out;
    float* cp  = (float*)d_ws;   // 2048*512*4 = 4 MB scratch for c_proj

    // Kernel 1: 32 M-tiles x 8 N-tiles = 256 blocks, bf16 MFMA
    cproj_mfma<<<dim3(256), dim3(256), 0, stream>>>(c, W, bias, kptr, cp);
    // Kernel 2: one block per (b,s) row = 2048 blocks, 4 waves, 4-deep pipeline
    dot_kernel<<<dim3(2048), dim3(256), 0, stream>>>(z, cp, out);
}